// Round 1
// baseline (919.022 us; speedup 1.0000x reference)
//
#include <hip/hip_runtime.h>
#include <math.h>

#define ZD 256      // z_dim (C)
#define KC 1024     // number of codes
#define TT 4096     // T
#define BB 16       // B
#define NROWS (BB*TT)     // 65536
#define LDSP 260          // padded LDS row stride (floats): 256+4, keeps 16B align, <=2-way conflicts

// ---------------- ||e||^2 per code ----------------
__global__ __launch_bounds__(256)
void vq_re_kernel(const float* __restrict__ emb, float* __restrict__ re) {
    int gw   = (blockIdx.x * 256 + threadIdx.x) >> 6;   // one wave per code (1024 waves)
    int lane = threadIdx.x & 63;
    float4 v = *(const float4*)(emb + (size_t)gw * ZD + lane * 4);
    float s = v.x*v.x + v.y*v.y + v.z*v.z + v.w*v.w;
    #pragma unroll
    for (int off = 32; off; off >>= 1) s += __shfl_down(s, off, 64);
    if (lane == 0) re[gw] = s;
}

// ---------------- main argmin (distance) kernel ----------------
// grid: 1024 blocks (64 rows each), 256 threads.
// Each thread: rows {16*i+rg}, codes {tile*64 + 16*j+cg}, 4x4 fp32 accumulators.
__global__ __launch_bounds__(256)
void vq_argmin_kernel(const float* __restrict__ z, const float* __restrict__ emb,
                      const float* __restrict__ re, int* __restrict__ idx,
                      float* __restrict__ hist) {
    __shared__ __align__(16) float zs[64 * LDSP];
    __shared__ __align__(16) float es[64 * LDSP];

    const int tid = threadIdx.x;
    const int r0  = blockIdx.x * 64;
    const int b   = r0 >> 12;        // 4096 rows per b, 64-row blocks never straddle b
    const int t0  = r0 & 4095;
    const float* zb = z + (size_t)b * ZD * TT + t0;

    // stage z tile: zs[row][c] = z[b][c][t0+row]; coalesced along t
    {
        const int lane = tid & 63;
        for (int c = (tid >> 6); c < ZD; c += 4) {
            zs[lane * LDSP + c] = zb[(size_t)c * TT + lane];
        }
    }

    const int rg = tid >> 4;   // 0..15 row group
    const int cg = tid & 15;   // 0..15 code group

    float minv[4];
    int   mini[4];
    #pragma unroll
    for (int i = 0; i < 4; ++i) { minv[i] = 3.4e38f; mini[i] = 0; }

    for (int ct = 0; ct < KC / 64; ++ct) {
        __syncthreads();   // protect es (and first-iter zs) before rewrite
        {
            const float* eb = emb + (size_t)ct * 64 * ZD;
            #pragma unroll
            for (int i = tid * 4; i < 64 * ZD; i += 1024) {
                float4 v = *(const float4*)(eb + i);
                int cc = i >> 8, kk = i & 255;
                *(float4*)&es[cc * LDSP + kk] = v;
            }
        }
        __syncthreads();

        float acc[4][4];
        #pragma unroll
        for (int i = 0; i < 4; ++i)
            #pragma unroll
            for (int j = 0; j < 4; ++j) acc[i][j] = 0.f;

        const float* zp = zs + rg * LDSP;
        const float* ep = es + cg * LDSP;
        #pragma unroll 4
        for (int k = 0; k < ZD; k += 4) {
            float4 za[4], ea[4];
            #pragma unroll
            for (int i = 0; i < 4; ++i) za[i] = *(const float4*)(zp + i * 16 * LDSP + k);
            #pragma unroll
            for (int j = 0; j < 4; ++j) ea[j] = *(const float4*)(ep + j * 16 * LDSP + k);
            #pragma unroll
            for (int i = 0; i < 4; ++i)
                #pragma unroll
                for (int j = 0; j < 4; ++j) {
                    acc[i][j] = fmaf(za[i].x, ea[j].x, acc[i][j]);
                    acc[i][j] = fmaf(za[i].y, ea[j].y, acc[i][j]);
                    acc[i][j] = fmaf(za[i].z, ea[j].z, acc[i][j]);
                    acc[i][j] = fmaf(za[i].w, ea[j].w, acc[i][j]);
                }
        }

        // argmin update: s = ||e||^2 - 2*dot (row-constant ||z||^2 dropped)
        #pragma unroll
        for (int j = 0; j < 4; ++j) {
            int c = ct * 64 + 16 * j + cg;
            float rc = re[c];
            #pragma unroll
            for (int i = 0; i < 4; ++i) {
                float s = rc - 2.0f * acc[i][j];
                if (s < minv[i]) { minv[i] = s; mini[i] = c; }
            }
        }
    }

    // reduce across the 16 lanes sharing the same rows (cg = 0..15)
    #pragma unroll
    for (int i = 0; i < 4; ++i) {
        float v  = minv[i];
        int   ix = mini[i];
        #pragma unroll
        for (int off = 8; off; off >>= 1) {
            float ov = __shfl_xor(v, off, 64);
            int   oi = __shfl_xor(ix, off, 64);
            if (ov < v || (ov == v && oi < ix)) { v = ov; ix = oi; }
        }
        if (cg == 0) {
            int r = r0 + 16 * i + rg;
            idx[r] = ix;
            atomicAdd(&hist[ix], 1.0f);
        }
    }
}

// ---------------- scatter z_vq to (B,C,T) + losses ----------------
__global__ __launch_bounds__(256)
void vq_scatter_kernel(const float* __restrict__ z, const float* __restrict__ emb,
                       const int* __restrict__ idx, float* __restrict__ out,
                       float* __restrict__ scal) {
    const int b   = blockIdx.x >> 4;
    const int tch = blockIdx.x & 15;
    const int t   = (tch << 8) + threadIdx.x;
    const int row = (b << 12) + t;
    const int ii  = idx[row];
    const float4* er = (const float4*)(emb + (size_t)ii * ZD);
    const size_t base = ((size_t)b << 20) + (size_t)t;   // b*C*T + t

    float lsum = 0.f;
    #pragma unroll 4
    for (int c4 = 0; c4 < ZD / 4; ++c4) {
        float4 ev = er[c4];
        size_t a0 = base + ((size_t)c4 << 14);           // (4*c4)*4096
        float d;
        d = ev.x - z[a0];            out[a0]          = ev.x; lsum = fmaf(d, d, lsum);
        d = ev.y - z[a0 + 4096];     out[a0 + 4096]   = ev.y; lsum = fmaf(d, d, lsum);
        d = ev.z - z[a0 + 8192];     out[a0 + 8192]   = ev.z; lsum = fmaf(d, d, lsum);
        d = ev.w - z[a0 + 12288];    out[a0 + 12288]  = ev.w; lsum = fmaf(d, d, lsum);
    }
    #pragma unroll
    for (int off = 32; off; off >>= 1) lsum += __shfl_down(lsum, off, 64);
    __shared__ float wred[4];
    if ((threadIdx.x & 63) == 0) wred[threadIdx.x >> 6] = lsum;
    __syncthreads();
    if (threadIdx.x == 0) {
        float tt = wred[0] + wred[1] + wred[2] + wred[3];
        atomicAdd(scal + 0, tt);   // z_qut_loss
        atomicAdd(scal + 1, tt);   // z_enc_loss (same forward value)
    }
}

// ---------------- perplexity ----------------
__global__ __launch_bounds__(256)
void vq_perplexity_kernel(const float* __restrict__ hist, float* __restrict__ outp) {
    __shared__ float red[256];
    float s = 0.f;
    for (int j = threadIdx.x; j < KC; j += 256) {
        float p = hist[j] * (1.0f / (float)NROWS);
        s -= p * logf(p + 1e-10f);
    }
    red[threadIdx.x] = s;
    __syncthreads();
    for (int st = 128; st > 0; st >>= 1) {
        if (threadIdx.x < st) red[threadIdx.x] += red[threadIdx.x + st];
        __syncthreads();
    }
    if (threadIdx.x == 0) outp[0] = expf(red[0]);
}

// ---------------- sparsity: mean(logsumexp(E E^T row) - diag) ----------------
__global__ __launch_bounds__(256)
void vq_sparsity_kernel(const float* __restrict__ emb, float* __restrict__ outp) {
    const int r   = blockIdx.x;     // 1024 rows
    const int tid = threadIdx.x;
    __shared__ __align__(16) float er[ZD];
    __shared__ float red[256];
    __shared__ float sdiag;

    er[tid] = emb[(size_t)r * ZD + tid];
    __syncthreads();

    float dots[4];
    #pragma unroll
    for (int j = 0; j < 4; ++j) {
        int c = j * 256 + tid;
        const float4* ec = (const float4*)(emb + (size_t)c * ZD);
        float s = 0.f;
        #pragma unroll 4
        for (int k4 = 0; k4 < ZD / 4; ++k4) {
            float4 e4 = ec[k4];
            float4 a4 = *(const float4*)&er[k4 * 4];
            s = fmaf(e4.x, a4.x, s);
            s = fmaf(e4.y, a4.y, s);
            s = fmaf(e4.z, a4.z, s);
            s = fmaf(e4.w, a4.w, s);
        }
        dots[j] = s;
    }
    if (tid == (r & 255)) sdiag = dots[r >> 8];

    float m4 = fmaxf(fmaxf(dots[0], dots[1]), fmaxf(dots[2], dots[3]));
    red[tid] = m4;
    __syncthreads();
    for (int st = 128; st > 0; st >>= 1) {
        if (tid < st) red[tid] = fmaxf(red[tid], red[tid + st]);
        __syncthreads();
    }
    float M = red[0];
    __syncthreads();
    float se = expf(dots[0] - M) + expf(dots[1] - M) + expf(dots[2] - M) + expf(dots[3] - M);
    red[tid] = se;
    __syncthreads();
    for (int st = 128; st > 0; st >>= 1) {
        if (tid < st) red[tid] += red[tid + st];
        __syncthreads();
    }
    if (tid == 0) {
        float lse = M + logf(red[0]);
        atomicAdd(outp, (lse - sdiag) * (1.0f / (float)KC));
    }
}

extern "C" void kernel_launch(void* const* d_in, const int* in_sizes, int n_in,
                              void* d_out, int out_size, void* d_ws, size_t ws_size,
                              hipStream_t stream) {
    const float* z   = (const float*)d_in[0];
    const float* emb = (const float*)d_in[1];
    float* out = (float*)d_out;
    const size_t NOUT = (size_t)BB * ZD * TT;    // 16777216
    float* scal = out + NOUT;                    // [qut, enc, perp, sparsity]

    float* re   = (float*)d_ws;                  // 1024 floats
    float* hist = re + KC;                       // 1024 floats
    int*   idx  = (int*)(hist + KC);             // 65536 ints

    hipMemsetAsync(hist, 0, KC * sizeof(float), stream);
    hipMemsetAsync(scal, 0, 4 * sizeof(float), stream);

    vq_re_kernel<<<KC / 4, 256, 0, stream>>>(emb, re);
    vq_argmin_kernel<<<NROWS / 64, 256, 0, stream>>>(z, emb, re, idx, hist);
    vq_perplexity_kernel<<<1, 256, 0, stream>>>(hist, scal + 2);
    vq_sparsity_kernel<<<KC, 256, 0, stream>>>(emb, scal + 3);
    vq_scatter_kernel<<<(BB * TT) / 256, 256, 0, stream>>>(z, emb, idx, out, scal);
}

// Round 2
// 538.714 us; speedup vs baseline: 1.7060x; 1.7060x over previous
//
#include <hip/hip_runtime.h>
#include <math.h>

typedef unsigned int u32;
typedef _Float16 f16x8 __attribute__((ext_vector_type(8)));
typedef _Float16 f16x4 __attribute__((ext_vector_type(4)));
typedef _Float16 f16x2 __attribute__((ext_vector_type(2)));
typedef float f32x4 __attribute__((ext_vector_type(4)));

#define ZD 256      // z_dim (C)
#define KC 1024     // number of codes
#define TT 4096     // T
#define BB 16       // B
#define NROWS (BB*TT)     // 65536
#define TAU 0.015f        // margin threshold for exact-fp32 rescore
#define FLAGCAP 8192

// ---------------- prep: re = ||e||^2 ; convert emb -> fp16 hi/lo ----------------
__global__ __launch_bounds__(256)
void vq_prep_kernel(const float* __restrict__ emb, _Float16* __restrict__ eh,
                    _Float16* __restrict__ el, float* __restrict__ re) {
    int code = (blockIdx.x * 256 + threadIdx.x) >> 6;   // one wave per code
    int lane = threadIdx.x & 63;
    float4 v = *(const float4*)(emb + (size_t)code * ZD + lane * 4);
    float s = v.x*v.x + v.y*v.y + v.z*v.z + v.w*v.w;
    #pragma unroll
    for (int off = 32; off; off >>= 1) s += __shfl_down(s, off, 64);
    if (lane == 0) re[code] = s;

    f16x4 hv, lv;
    hv[0] = (_Float16)v.x; lv[0] = (_Float16)(v.x - (float)hv[0]);
    hv[1] = (_Float16)v.y; lv[1] = (_Float16)(v.y - (float)hv[1]);
    hv[2] = (_Float16)v.z; lv[2] = (_Float16)(v.z - (float)hv[2]);
    hv[3] = (_Float16)v.w; lv[3] = (_Float16)(v.w - (float)hv[3]);
    *(f16x4*)(eh + (size_t)code * ZD + lane * 4) = hv;
    *(f16x4*)(el + (size_t)code * ZD + lane * 4) = lv;
}

// ---------------- main argmin via fp16-split MFMA ----------------
// 2048 blocks x 256 threads. Block: 32 rows. Wave w: codes [256w, 256w+256).
// acc tile per wave: 32 rows x 256 codes = 2 rowgroups x 16 codegroups of 16x16.
// dot = zh*eh + zh*el + zl*eh (fp32 accum); s = ||e||^2 - 2*dot.
__global__ __launch_bounds__(256, 2)
void vq_argmin_mfma(const float* __restrict__ z, const _Float16* __restrict__ eh,
                    const _Float16* __restrict__ el, const float* __restrict__ re,
                    int* __restrict__ idx, int* __restrict__ cnt, int* __restrict__ flags) {
    __shared__ u32 zsh[32 * 128];   // fp16 hi, k-pair packed, XOR-swizzled
    __shared__ u32 zsl[32 * 128];   // fp16 lo
    __shared__ float redv1[4][32];
    __shared__ float redv2[4][32];
    __shared__ int   redi1[4][32];

    const int tid = threadIdx.x;
    const int w   = tid >> 6;
    const int l   = tid & 63;
    const int r0  = blockIdx.x * 32;
    const int b   = r0 >> 12;
    const int t0  = r0 & 4095;
    const float* zb = z + (size_t)b * ZD * TT + t0;

    // ---- stage z tile: zs*[t][c2 ^ swz(t)] = packed fp16 pair (k=2c2, 2c2+1)
    {
        const int t   = tid & 31;
        const int c2b = tid >> 5;   // 0..7
        const int swz = (t & 7) << 2;
        #pragma unroll 4
        for (int j = 0; j < 16; ++j) {
            int c2 = c2b * 16 + j;          // 0..127
            float v0 = zb[(size_t)(2 * c2) * TT + t];
            float v1 = zb[(size_t)(2 * c2 + 1) * TT + t];
            _Float16 h0 = (_Float16)v0, h1 = (_Float16)v1;
            _Float16 l0 = (_Float16)(v0 - (float)h0);
            _Float16 l1 = (_Float16)(v1 - (float)h1);
            f16x2 hp = {h0, h1}, lp = {l0, l1};
            int ci = c2 ^ swz;
            zsh[t * 128 + ci] = __builtin_bit_cast(u32, hp);
            zsl[t * 128 + ci] = __builtin_bit_cast(u32, lp);
        }
    }
    __syncthreads();

    const int lane15 = l & 15;
    const int lk     = l >> 4;          // 0..3 (k-group)
    const int cbase  = w * 256;

    f32x4 acc[2][16];
    #pragma unroll
    for (int rg = 0; rg < 2; ++rg)
        #pragma unroll
        for (int cg = 0; cg < 16; ++cg) acc[rg][cg] = (f32x4){0.f, 0.f, 0.f, 0.f};

    const size_t ebase = (size_t)(cbase + lane15) * ZD + lk * 8;

    for (int kc = 0; kc < 8; ++kc) {
        f16x8 ah[2], al[2];
        #pragma unroll
        for (int rg = 0; rg < 2; ++rg) {
            int row = rg * 16 + lane15;
            int off = (kc * 16 + lk * 4) ^ ((row & 7) << 2);
            ah[rg] = *(const f16x8*)&zsh[row * 128 + off];
            al[rg] = *(const f16x8*)&zsl[row * 128 + off];
        }
        #pragma unroll
        for (int cg = 0; cg < 16; ++cg) {
            size_t eo = ebase + (size_t)cg * 16 * ZD + kc * 32;
            f16x8 bh = *(const f16x8*)(eh + eo);
            f16x8 bl = *(const f16x8*)(el + eo);
            acc[0][cg] = __builtin_amdgcn_mfma_f32_16x16x32_f16(ah[0], bh, acc[0][cg], 0, 0, 0);
            acc[1][cg] = __builtin_amdgcn_mfma_f32_16x16x32_f16(ah[1], bh, acc[1][cg], 0, 0, 0);
            acc[0][cg] = __builtin_amdgcn_mfma_f32_16x16x32_f16(ah[0], bl, acc[0][cg], 0, 0, 0);
            acc[1][cg] = __builtin_amdgcn_mfma_f32_16x16x32_f16(ah[1], bl, acc[1][cg], 0, 0, 0);
            acc[0][cg] = __builtin_amdgcn_mfma_f32_16x16x32_f16(al[0], bh, acc[0][cg], 0, 0, 0);
            acc[1][cg] = __builtin_amdgcn_mfma_f32_16x16x32_f16(al[1], bh, acc[1][cg], 0, 0, 0);
        }
    }

    // ---- epilogue: s = re - 2*dot ; per-row top-2 (value, index)
    // D layout (16x16): col = l&15 (code), row = lk*4 + reg.  slot = rg*4 + r.
    float v1r[8], v2r[8];
    int   i1r[8];
    #pragma unroll
    for (int s8 = 0; s8 < 8; ++s8) { v1r[s8] = 3.4e38f; v2r[s8] = 3.4e38f; i1r[s8] = 0; }

    #pragma unroll
    for (int cg = 0; cg < 16; ++cg) {
        int code = cbase + cg * 16 + lane15;
        float rc = re[code];
        #pragma unroll
        for (int rg = 0; rg < 2; ++rg) {
            f32x4 a = acc[rg][cg];
            #pragma unroll
            for (int r = 0; r < 4; ++r) {
                float s = fmaf(-2.0f, a[r], rc);
                int slot = rg * 4 + r;
                if (s < v1r[slot]) { v2r[slot] = v1r[slot]; v1r[slot] = s; i1r[slot] = code; }
                else if (s < v2r[slot]) v2r[slot] = s;
            }
        }
    }

    // reduce across the 16 lanes holding different codes (same rows)
    #pragma unroll
    for (int off = 1; off < 16; off <<= 1) {
        #pragma unroll
        for (int s8 = 0; s8 < 8; ++s8) {
            float ov1 = __shfl_xor(v1r[s8], off, 64);
            int   oi1 = __shfl_xor(i1r[s8], off, 64);
            float ov2 = __shfl_xor(v2r[s8], off, 64);
            float nv2 = fminf(fmaxf(v1r[s8], ov1), fminf(v2r[s8], ov2));
            if (ov1 < v1r[s8] || (ov1 == v1r[s8] && oi1 < i1r[s8])) { v1r[s8] = ov1; i1r[s8] = oi1; }
            v2r[s8] = nv2;
        }
    }
    if (lane15 == 0) {
        #pragma unroll
        for (int s8 = 0; s8 < 8; ++s8) {
            int rg = s8 >> 2, r = s8 & 3;
            int row = rg * 16 + lk * 4 + r;
            redv1[w][row] = v1r[s8];
            redv2[w][row] = v2r[s8];
            redi1[w][row] = i1r[s8];
        }
    }
    __syncthreads();
    if (tid < 32) {
        float bv1 = redv1[0][tid], bv2 = redv2[0][tid];
        int   bi1 = redi1[0][tid];
        #pragma unroll
        for (int ww = 1; ww < 4; ++ww) {
            float ov1 = redv1[ww][tid], ov2 = redv2[ww][tid];
            int   oi1 = redi1[ww][tid];
            float nv2 = fminf(fmaxf(bv1, ov1), fminf(bv2, ov2));
            if (ov1 < bv1 || (ov1 == bv1 && oi1 < bi1)) { bv1 = ov1; bi1 = oi1; }
            bv2 = nv2;
        }
        int row = r0 + tid;
        idx[row] = bi1;
        if (bv2 - bv1 < TAU) {
            int pos = atomicAdd(cnt, 1);
            if (pos < FLAGCAP) flags[pos] = row;
        }
    }
}

// ---------------- exact fp32 rescore for flagged (near-tie) rows ----------------
__global__ __launch_bounds__(256)
void vq_fixup_kernel(const float* __restrict__ z, const float* __restrict__ emb,
                     const float* __restrict__ re, const int* __restrict__ cnt,
                     const int* __restrict__ flags, int* __restrict__ idx) {
    __shared__ float zrow[ZD];
    __shared__ float rv[256];
    __shared__ int   ri[256];
    const int tid = threadIdx.x;
    int n = *cnt;
    if (n > FLAGCAP) n = FLAGCAP;
    for (int f = blockIdx.x; f < n; f += gridDim.x) {
        int r = flags[f];
        int b = r >> 12, t = r & 4095;
        __syncthreads();
        zrow[tid & 255] = z[(size_t)b * ZD * TT + (size_t)(tid & 255) * TT + t];
        __syncthreads();
        float best = 3.4e38f; int bi = 0;
        for (int c = tid; c < KC; c += 256) {
            const float* ec = emb + (size_t)c * ZD;
            float s = 0.f;
            #pragma unroll 8
            for (int k = 0; k < ZD; ++k) s = fmaf(zrow[k], ec[k], s);
            float d = fmaf(-2.0f, s, re[c]);
            if (d < best || (d == best && c < bi)) { best = d; bi = c; }
        }
        rv[tid] = best; ri[tid] = bi;
        __syncthreads();
        for (int st = 128; st; st >>= 1) {
            if (tid < st) {
                float ov = rv[tid + st]; int oi = ri[tid + st];
                if (ov < rv[tid] || (ov == rv[tid] && oi < ri[tid])) { rv[tid] = ov; ri[tid] = oi; }
            }
            __syncthreads();
        }
        if (tid == 0) idx[r] = ri[0];
    }
}

// ---------------- scatter z_vq to (B,C,T) + losses + histogram ----------------
__global__ __launch_bounds__(256)
void vq_scatter_kernel(const float* __restrict__ z, const float* __restrict__ emb,
                       const int* __restrict__ idx, float* __restrict__ out,
                       float* __restrict__ scal, float* __restrict__ hist) {
    const int b   = blockIdx.x >> 4;
    const int tch = blockIdx.x & 15;
    const int t   = (tch << 8) + threadIdx.x;
    const int row = (b << 12) + t;
    const int ii  = idx[row];
    const float4* er = (const float4*)(emb + (size_t)ii * ZD);
    const size_t base = ((size_t)b << 20) + (size_t)t;   // b*C*T + t

    atomicAdd(&hist[ii], 1.0f);

    float lsum = 0.f;
    #pragma unroll 4
    for (int c4 = 0; c4 < ZD / 4; ++c4) {
        float4 ev = er[c4];
        size_t a0 = base + ((size_t)c4 << 14);           // (4*c4)*4096
        float d;
        d = ev.x - z[a0];            out[a0]          = ev.x; lsum = fmaf(d, d, lsum);
        d = ev.y - z[a0 + 4096];     out[a0 + 4096]   = ev.y; lsum = fmaf(d, d, lsum);
        d = ev.z - z[a0 + 8192];     out[a0 + 8192]   = ev.z; lsum = fmaf(d, d, lsum);
        d = ev.w - z[a0 + 12288];    out[a0 + 12288]  = ev.w; lsum = fmaf(d, d, lsum);
    }
    #pragma unroll
    for (int off = 32; off; off >>= 1) lsum += __shfl_down(lsum, off, 64);
    __shared__ float wred[4];
    if ((threadIdx.x & 63) == 0) wred[threadIdx.x >> 6] = lsum;
    __syncthreads();
    if (threadIdx.x == 0) {
        float tt = wred[0] + wred[1] + wred[2] + wred[3];
        atomicAdd(scal + 0, tt);   // z_qut_loss
        atomicAdd(scal + 1, tt);   // z_enc_loss (same forward value)
    }
}

// ---------------- perplexity ----------------
__global__ __launch_bounds__(256)
void vq_perplexity_kernel(const float* __restrict__ hist, float* __restrict__ outp) {
    __shared__ float red[256];
    float s = 0.f;
    for (int j = threadIdx.x; j < KC; j += 256) {
        float p = hist[j] * (1.0f / (float)NROWS);
        s -= p * logf(p + 1e-10f);
    }
    red[threadIdx.x] = s;
    __syncthreads();
    for (int st = 128; st > 0; st >>= 1) {
        if (threadIdx.x < st) red[threadIdx.x] += red[threadIdx.x + st];
        __syncthreads();
    }
    if (threadIdx.x == 0) outp[0] = expf(red[0]);
}

// ---------------- sparsity: mean(logsumexp(E E^T row) - diag) ----------------
__global__ __launch_bounds__(256)
void vq_sparsity_kernel(const float* __restrict__ emb, float* __restrict__ outp) {
    const int r   = blockIdx.x;     // 1024 rows
    const int tid = threadIdx.x;
    __shared__ __align__(16) float er[ZD];
    __shared__ float red[256];
    __shared__ float sdiag;

    er[tid] = emb[(size_t)r * ZD + tid];
    __syncthreads();

    float dots[4];
    #pragma unroll
    for (int j = 0; j < 4; ++j) {
        int c = j * 256 + tid;
        const float4* ec = (const float4*)(emb + (size_t)c * ZD);
        float s = 0.f;
        #pragma unroll 4
        for (int k4 = 0; k4 < ZD / 4; ++k4) {
            float4 e4 = ec[k4];
            float4 a4 = *(const float4*)&er[k4 * 4];
            s = fmaf(e4.x, a4.x, s);
            s = fmaf(e4.y, a4.y, s);
            s = fmaf(e4.z, a4.z, s);
            s = fmaf(e4.w, a4.w, s);
        }
        dots[j] = s;
    }
    if (tid == (r & 255)) sdiag = dots[r >> 8];

    float m4 = fmaxf(fmaxf(dots[0], dots[1]), fmaxf(dots[2], dots[3]));
    red[tid] = m4;
    __syncthreads();
    for (int st = 128; st > 0; st >>= 1) {
        if (tid < st) red[tid] = fmaxf(red[tid], red[tid + st]);
        __syncthreads();
    }
    float M = red[0];
    __syncthreads();
    float se = expf(dots[0] - M) + expf(dots[1] - M) + expf(dots[2] - M) + expf(dots[3] - M);
    red[tid] = se;
    __syncthreads();
    for (int st = 128; st > 0; st >>= 1) {
        if (tid < st) red[tid] += red[tid + st];
        __syncthreads();
    }
    if (tid == 0) {
        float lse = M + logf(red[0]);
        atomicAdd(outp, (lse - sdiag) * (1.0f / (float)KC));
    }
}

extern "C" void kernel_launch(void* const* d_in, const int* in_sizes, int n_in,
                              void* d_out, int out_size, void* d_ws, size_t ws_size,
                              hipStream_t stream) {
    const float* z   = (const float*)d_in[0];
    const float* emb = (const float*)d_in[1];
    float* out = (float*)d_out;
    const size_t NOUT = (size_t)BB * ZD * TT;    // 16777216
    float* scal = out + NOUT;                    // [qut, enc, perp, sparsity]

    float* re    = (float*)d_ws;                 // 1024 f32
    float* hist  = re + KC;                      // 1024 f32
    int*   idx   = (int*)(hist + KC);            // 65536 i32
    int*   cnt   = idx + NROWS;                  // 4 i32 (16B)
    int*   flags = cnt + 4;                      // FLAGCAP i32
    _Float16* eh = (_Float16*)(flags + FLAGCAP); // 1024*256 f16
    _Float16* el = eh + (size_t)KC * ZD;         // 1024*256 f16

    hipMemsetAsync(hist, 0, KC * sizeof(float), stream);
    hipMemsetAsync(cnt, 0, 16, stream);
    hipMemsetAsync(scal, 0, 4 * sizeof(float), stream);

    vq_prep_kernel<<<KC / 4, 256, 0, stream>>>(emb, eh, el, re);
    vq_argmin_mfma<<<NROWS / 32, 256, 0, stream>>>(z, eh, el, re, idx, cnt, flags);
    vq_fixup_kernel<<<64, 256, 0, stream>>>(z, emb, re, cnt, flags, idx);
    vq_sparsity_kernel<<<KC, 256, 0, stream>>>(emb, scal + 3);
    vq_scatter_kernel<<<(BB * TT) / 256, 256, 0, stream>>>(z, emb, idx, out, scal, hist);
    vq_perplexity_kernel<<<1, 256, 0, stream>>>(hist, scal + 2);
}

// Round 3
// 315.487 us; speedup vs baseline: 2.9130x; 1.7076x over previous
//
#include <hip/hip_runtime.h>
#include <math.h>

typedef unsigned int u32;
typedef _Float16 f16x8 __attribute__((ext_vector_type(8)));
typedef _Float16 f16x4 __attribute__((ext_vector_type(4)));
typedef float f32x4 __attribute__((ext_vector_type(4)));
typedef __attribute__((address_space(1))) const char gch;
typedef __attribute__((address_space(3))) char lch;

#define ZD 256      // z_dim (C)
#define KC 1024     // number of codes
#define TT 4096     // T
#define BB 16       // B
#define NROWS (BB*TT)     // 65536
#define TAU 0.004f        // margin threshold for exact-fp32 rescore
#define FLAGCAP 8192

// ---------------- prep: re=||e||^2, emb->fp16 hi/lo, zero hist/cnt/scal ----------------
__global__ __launch_bounds__(256)
void vq_prep_kernel(const float* __restrict__ emb, _Float16* __restrict__ eh,
                    _Float16* __restrict__ el, float* __restrict__ re,
                    float* __restrict__ hist, int* __restrict__ cnt,
                    float* __restrict__ scal) {
    int gid  = blockIdx.x * 256 + threadIdx.x;
    if (gid < KC) hist[gid] = 0.f;
    if (gid < 4)  scal[gid] = 0.f;
    if (gid == 0) cnt[0] = 0;

    int code = gid >> 6;   // one wave per code
    int lane = threadIdx.x & 63;
    float4 v = *(const float4*)(emb + (size_t)code * ZD + lane * 4);
    float s = v.x*v.x + v.y*v.y + v.z*v.z + v.w*v.w;
    #pragma unroll
    for (int off = 32; off; off >>= 1) s += __shfl_down(s, off, 64);
    if (lane == 0) re[code] = s;

    f16x4 hv, lv;
    hv[0] = (_Float16)v.x; lv[0] = (_Float16)(v.x - (float)hv[0]);
    hv[1] = (_Float16)v.y; lv[1] = (_Float16)(v.y - (float)hv[1]);
    hv[2] = (_Float16)v.z; lv[2] = (_Float16)(v.z - (float)hv[2]);
    hv[3] = (_Float16)v.w; lv[3] = (_Float16)(v.w - (float)hv[3]);
    *(f16x4*)(eh + (size_t)code * ZD + lane * 4) = hv;
    *(f16x4*)(el + (size_t)code * ZD + lane * 4) = lv;
}

// ---- stage one 32-code tile (h+l, 32KB) via global_load_lds, swizzled source ----
__device__ __forceinline__ void stage_tile(const char* ehc, const char* elc,
                                           char* dstbase, int tile, int w, int l) {
    const int srow = tile * 16384;          // 32 codes * 512B
    #pragma unroll
    for (int j = 0; j < 8; ++j) {
        const int gi  = w * 8 + j;          // 0..31
        const int hl  = gi >> 4;            // 0=h, 1=l
        const int i16 = gi & 15;
        const int c   = 2 * i16 + (l >> 5); // local code this lane's 16B lands in
        const int kbs = (l & 31) * 16;      // byte offset within code row
        const int off = srow + c * 512 + (kbs ^ ((c & 7) << 4));
        const char* g = (hl ? elc : ehc) + off;
        char* dst = dstbase + hl * 16384 + i16 * 1024;   // wave-uniform
        __builtin_amdgcn_global_load_lds((gch*)g, (lch*)dst, 16, 0, 0);
    }
}

// ---------------- main argmin via fp16-split MFMA, e staged in LDS ----------------
// 512 blocks x 256 threads. Block: 128 rows; wave w: rows [32w,32w+32).
// Code loop: 32 tiles x 32 codes, double-buffered LDS, counted vmcnt.
__global__ __launch_bounds__(256, 2)
void vq_argmin_mfma(const float* __restrict__ z, const _Float16* __restrict__ eh,
                    const _Float16* __restrict__ el, const float* __restrict__ re,
                    int* __restrict__ idx, int* __restrict__ cnt, int* __restrict__ flags) {
    __shared__ __align__(16) char lds[69632];   // 2 x 32KB e-buf + 4KB re

    const int tid = threadIdx.x;
    const int w   = tid >> 6;
    const int l   = tid & 63;
    const int lane15 = l & 15;
    const int lk     = l >> 4;
    const int r0  = blockIdx.x * 128;
    const int b   = r0 >> 12;
    const int t0  = r0 & 4095;
    const char* ehc = (const char*)eh;
    const char* elc = (const char*)el;

    // re -> LDS (4KB)
    float* reL = (float*)(lds + 65536);
    *(float4*)(reL + tid * 4) = *(const float4*)(re + tid * 4);

    // z A-fragments direct from global, fp16 hi/lo split, kept in registers
    f16x8 ah[2][8], al[2][8];
    {
        const float* zw = z + (size_t)b * ZD * TT + t0 + w * 32;
        #pragma unroll
        for (int rg = 0; rg < 2; ++rg) {
            const float* zr = zw + rg * 16 + lane15;
            #pragma unroll
            for (int ks = 0; ks < 8; ++ks) {
                const int kb = ks * 32 + lk * 8;
                f16x8 h, lo;
                #pragma unroll
                for (int j = 0; j < 8; ++j) {
                    float v = zr[(size_t)(kb + j) * TT];
                    _Float16 hh = (_Float16)v;
                    h[j]  = hh;
                    lo[j] = (_Float16)(v - (float)hh);
                }
                ah[rg][ks] = h; al[rg][ks] = lo;
            }
        }
    }

    float v1[8], v2[8];
    int   i1[8];
    #pragma unroll
    for (int s8 = 0; s8 < 8; ++s8) { v1[s8] = 3.4e38f; v2[s8] = 3.4e38f; i1[s8] = 0; }

    __syncthreads();                 // re visible; drain prologue loads
    stage_tile(ehc, elc, lds, 0, w, l);

    for (int t = 0; t < 32; ++t) {
        const int cur = t & 1;
        if (t < 31) {
            stage_tile(ehc, elc, lds + ((cur ^ 1) << 15), t + 1, w, l);
            asm volatile("s_waitcnt vmcnt(8)" ::: "memory");
        } else {
            asm volatile("s_waitcnt vmcnt(0)" ::: "memory");
        }
        __builtin_amdgcn_sched_barrier(0);
        __builtin_amdgcn_s_barrier();

        const char* hb = lds + (cur << 15);
        const char* lb = hb + 16384;
        #pragma unroll
        for (int cg = 0; cg < 2; ++cg) {
            f32x4 a0 = {0.f, 0.f, 0.f, 0.f};
            f32x4 a1 = {0.f, 0.f, 0.f, 0.f};
            const int c  = cg * 16 + lane15;        // local code
            const int sw = (c & 7) << 4;
            #pragma unroll
            for (int ks = 0; ks < 8; ++ks) {
                const int kb = (lk * 16 + ks * 64) ^ sw;
                f16x8 bh = *(const f16x8*)(hb + c * 512 + kb);
                f16x8 bl = *(const f16x8*)(lb + c * 512 + kb);
                a0 = __builtin_amdgcn_mfma_f32_16x16x32_f16(ah[0][ks], bh, a0, 0, 0, 0);
                a1 = __builtin_amdgcn_mfma_f32_16x16x32_f16(ah[1][ks], bh, a1, 0, 0, 0);
                a0 = __builtin_amdgcn_mfma_f32_16x16x32_f16(al[0][ks], bh, a0, 0, 0, 0);
                a1 = __builtin_amdgcn_mfma_f32_16x16x32_f16(al[1][ks], bh, a1, 0, 0, 0);
                a0 = __builtin_amdgcn_mfma_f32_16x16x32_f16(ah[0][ks], bl, a0, 0, 0, 0);
                a1 = __builtin_amdgcn_mfma_f32_16x16x32_f16(ah[1][ks], bl, a1, 0, 0, 0);
            }
            const int codeg = t * 32 + cg * 16 + lane15;
            const float rc = reL[codeg];
            #pragma unroll
            for (int r = 0; r < 4; ++r) {
                float s0 = fmaf(-2.f, a0[r], rc);
                if (s0 < v1[r]) { v2[r] = v1[r]; v1[r] = s0; i1[r] = codeg; }
                else if (s0 < v2[r]) v2[r] = s0;
                float s1 = fmaf(-2.f, a1[r], rc);
                if (s1 < v1[4 + r]) { v2[4 + r] = v1[4 + r]; v1[4 + r] = s1; i1[4 + r] = codeg; }
                else if (s1 < v2[4 + r]) v2[4 + r] = s1;
            }
        }
        __builtin_amdgcn_s_barrier();
        __builtin_amdgcn_sched_barrier(0);
    }

    // reduce across the 16 lanes holding different codes (same rows)
    #pragma unroll
    for (int off = 1; off < 16; off <<= 1) {
        #pragma unroll
        for (int s8 = 0; s8 < 8; ++s8) {
            float ov1 = __shfl_xor(v1[s8], off, 64);
            int   oi1 = __shfl_xor(i1[s8], off, 64);
            float ov2 = __shfl_xor(v2[s8], off, 64);
            float nv2 = fminf(fmaxf(v1[s8], ov1), fminf(v2[s8], ov2));
            if (ov1 < v1[s8] || (ov1 == v1[s8] && oi1 < i1[s8])) { v1[s8] = ov1; i1[s8] = oi1; }
            v2[s8] = nv2;
        }
    }
    if (lane15 == 0) {
        #pragma unroll
        for (int s8 = 0; s8 < 8; ++s8) {
            const int rg = s8 >> 2, rr = s8 & 3;
            const int row = r0 + w * 32 + rg * 16 + lk * 4 + rr;
            idx[row] = i1[s8];
            if (v2[s8] - v1[s8] < TAU) {
                int p = atomicAdd(cnt, 1);
                if (p < FLAGCAP) flags[p] = row;
            }
        }
    }
}

// ---------------- exact fp32 rescore for flagged (near-tie) rows ----------------
__global__ __launch_bounds__(256)
void vq_fixup_kernel(const float* __restrict__ z, const float* __restrict__ emb,
                     const float* __restrict__ re, const int* __restrict__ cnt,
                     const int* __restrict__ flags, int* __restrict__ idx) {
    __shared__ float zrow[ZD];
    __shared__ float rv[256];
    __shared__ int   ri[256];
    const int tid = threadIdx.x;
    int n = *cnt;
    if (n > FLAGCAP) n = FLAGCAP;
    for (int f = blockIdx.x; f < n; f += gridDim.x) {
        int r = flags[f];
        int b = r >> 12, t = r & 4095;
        __syncthreads();
        zrow[tid] = z[(size_t)b * ZD * TT + (size_t)tid * TT + t];
        __syncthreads();
        float best = 3.4e38f; int bi = 0;
        for (int c = tid; c < KC; c += 256) {
            const float* ec = emb + (size_t)c * ZD;
            float s = 0.f;
            #pragma unroll 8
            for (int k = 0; k < ZD; ++k) s = fmaf(zrow[k], ec[k], s);
            float d = fmaf(-2.0f, s, re[c]);
            if (d < best || (d == best && c < bi)) { best = d; bi = c; }
        }
        rv[tid] = best; ri[tid] = bi;
        __syncthreads();
        for (int st = 128; st; st >>= 1) {
            if (tid < st) {
                float ov = rv[tid + st]; int oi = ri[tid + st];
                if (ov < rv[tid] || (ov == rv[tid] && oi < ri[tid])) { rv[tid] = ov; ri[tid] = oi; }
            }
            __syncthreads();
        }
        if (tid == 0) idx[r] = ri[0];
        __syncthreads();
    }
}

// ---------------- scatter z_vq to (B,C,T) + losses + histogram ----------------
__global__ __launch_bounds__(256)
void vq_scatter_kernel(const float* __restrict__ z, const float* __restrict__ emb,
                       const int* __restrict__ idx, float* __restrict__ out,
                       float* __restrict__ scal, float* __restrict__ hist) {
    const int b   = blockIdx.x >> 4;
    const int tch = blockIdx.x & 15;
    const int t   = (tch << 8) + threadIdx.x;
    const int row = (b << 12) + t;
    const int ii  = idx[row];
    const float4* er = (const float4*)(emb + (size_t)ii * ZD);
    const size_t base = ((size_t)b << 20) + (size_t)t;   // b*C*T + t

    atomicAdd(&hist[ii], 1.0f);

    float lsum = 0.f;
    #pragma unroll 4
    for (int c4 = 0; c4 < ZD / 4; ++c4) {
        float4 ev = er[c4];
        size_t a0 = base + ((size_t)c4 << 14);           // (4*c4)*4096
        float d;
        d = ev.x - z[a0];            out[a0]          = ev.x; lsum = fmaf(d, d, lsum);
        d = ev.y - z[a0 + 4096];     out[a0 + 4096]   = ev.y; lsum = fmaf(d, d, lsum);
        d = ev.z - z[a0 + 8192];     out[a0 + 8192]   = ev.z; lsum = fmaf(d, d, lsum);
        d = ev.w - z[a0 + 12288];    out[a0 + 12288]  = ev.w; lsum = fmaf(d, d, lsum);
    }
    #pragma unroll
    for (int off = 32; off; off >>= 1) lsum += __shfl_down(lsum, off, 64);
    __shared__ float wred[4];
    if ((threadIdx.x & 63) == 0) wred[threadIdx.x >> 6] = lsum;
    __syncthreads();
    if (threadIdx.x == 0) {
        float tt = wred[0] + wred[1] + wred[2] + wred[3];
        atomicAdd(scal + 0, tt);   // z_qut_loss
        atomicAdd(scal + 1, tt);   // z_enc_loss (same forward value)
    }
}

// ---------------- perplexity ----------------
__global__ __launch_bounds__(256)
void vq_perplexity_kernel(const float* __restrict__ hist, float* __restrict__ outp) {
    __shared__ float red[256];
    float s = 0.f;
    for (int j = threadIdx.x; j < KC; j += 256) {
        float p = hist[j] * (1.0f / (float)NROWS);
        s -= p * logf(p + 1e-10f);
    }
    red[threadIdx.x] = s;
    __syncthreads();
    for (int st = 128; st > 0; st >>= 1) {
        if (threadIdx.x < st) red[threadIdx.x] += red[threadIdx.x + st];
        __syncthreads();
    }
    if (threadIdx.x == 0) outp[0] = expf(red[0]);
}

// ---------------- sparsity: mean(logsumexp(E E^T row) - diag), 8 rows/block ----------------
__global__ __launch_bounds__(256)
void vq_sparsity_kernel(const float* __restrict__ emb, float* __restrict__ outp) {
    const int tid = threadIdx.x;
    const int r0  = blockIdx.x * 8;       // 128 blocks
    __shared__ __align__(16) float er[8][260];
    __shared__ float red[256];
    __shared__ float shD[8];

    for (int i = tid; i < 8 * 256; i += 256) er[i >> 8][i & 255] = emb[(size_t)r0 * ZD + i];
    __syncthreads();

    float dots[4][8];
    #pragma unroll
    for (int cc = 0; cc < 4; ++cc) {
        int c = cc * 256 + tid;
        const float4* ec = (const float4*)(emb + (size_t)c * ZD);
        float a[8];
        #pragma unroll
        for (int r = 0; r < 8; ++r) a[r] = 0.f;
        for (int k4 = 0; k4 < ZD / 4; ++k4) {
            float4 e4 = ec[k4];
            #pragma unroll
            for (int r = 0; r < 8; ++r) {
                float4 a4 = *(const float4*)&er[r][k4 * 4];
                a[r] = fmaf(e4.x, a4.x, a[r]);
                a[r] = fmaf(e4.y, a4.y, a[r]);
                a[r] = fmaf(e4.z, a4.z, a[r]);
                a[r] = fmaf(e4.w, a4.w, a[r]);
            }
        }
        #pragma unroll
        for (int r = 0; r < 8; ++r) dots[cc][r] = a[r];
        int gr = c - r0;
        if (gr >= 0 && gr < 8) shD[gr] = a[gr];   // diag element
    }

    float acc = 0.f;
    for (int r = 0; r < 8; ++r) {
        float m = fmaxf(fmaxf(dots[0][r], dots[1][r]), fmaxf(dots[2][r], dots[3][r]));
        __syncthreads();
        red[tid] = m;
        __syncthreads();
        for (int st = 128; st > 0; st >>= 1) {
            if (tid < st) red[tid] = fmaxf(red[tid], red[tid + st]);
            __syncthreads();
        }
        float M = red[0];
        __syncthreads();
        float s = expf(dots[0][r] - M) + expf(dots[1][r] - M)
                + expf(dots[2][r] - M) + expf(dots[3][r] - M);
        red[tid] = s;
        __syncthreads();
        for (int st = 128; st > 0; st >>= 1) {
            if (tid < st) red[tid] += red[tid + st];
            __syncthreads();
        }
        if (tid == 0) acc += M + logf(red[0]) - shD[r];
        __syncthreads();
    }
    if (tid == 0) atomicAdd(outp, acc * (1.0f / (float)KC));
}

extern "C" void kernel_launch(void* const* d_in, const int* in_sizes, int n_in,
                              void* d_out, int out_size, void* d_ws, size_t ws_size,
                              hipStream_t stream) {
    const float* z   = (const float*)d_in[0];
    const float* emb = (const float*)d_in[1];
    float* out = (float*)d_out;
    const size_t NOUT = (size_t)BB * ZD * TT;    // 16777216
    float* scal = out + NOUT;                    // [qut, enc, perp, sparsity]

    float* re    = (float*)d_ws;                 // 1024 f32
    float* hist  = re + KC;                      // 1024 f32
    int*   idx   = (int*)(hist + KC);            // 65536 i32
    int*   cnt   = idx + NROWS;                  // 4 i32 (16B)
    int*   flags = cnt + 4;                      // FLAGCAP i32
    _Float16* eh = (_Float16*)(flags + FLAGCAP); // 1024*256 f16
    _Float16* el = eh + (size_t)KC * ZD;         // 1024*256 f16

    vq_prep_kernel<<<KC / 4, 256, 0, stream>>>(emb, eh, el, re, hist, cnt, scal);
    vq_argmin_mfma<<<NROWS / 128, 256, 0, stream>>>(z, eh, el, re, idx, cnt, flags);
    vq_fixup_kernel<<<256, 256, 0, stream>>>(z, emb, re, cnt, flags, idx);
    vq_sparsity_kernel<<<KC / 8, 256, 0, stream>>>(emb, scal + 3);
    vq_scatter_kernel<<<(BB * TT) / 256, 256, 0, stream>>>(z, emb, idx, out, scal, hist);
    vq_perplexity_kernel<<<1, 256, 0, stream>>>(hist, scal + 2);
}